// Round 1
// baseline (235.950 us; speedup 1.0000x reference)
//
#include <hip/hip_runtime.h>
#include <hip/hip_bf16.h>

#define N_NODES 50000
#define KNB 16
#define FDIM 128
#define HDIM 128
#define ALPHA 0.3f
#define BN_EPS 1e-3f

typedef __bf16 v8bf __attribute__((ext_vector_type(8)));
typedef float v4f __attribute__((ext_vector_type(4)));
typedef unsigned short ushort_t;

__device__ __forceinline__ float blo(unsigned int u) {
    union { float f; unsigned int i; } x; x.i = u << 16; return x.f;
}
__device__ __forceinline__ float bhi(unsigned int u) {
    union { float f; unsigned int i; } x; x.i = u & 0xffff0000u; return x.f;
}

__device__ __forceinline__ unsigned short f2bf(float f) {
    union { float f; unsigned int u; } x;
    x.f = f;
    unsigned int r = x.u + 0x7fffu + ((x.u >> 16) & 1u);  // RNE
    return (unsigned short)(r >> 16);
}

// packed f32x2 -> bf16x2 (RNE)
__device__ __forceinline__ unsigned int pk2(float a, float b) {
    __hip_bfloat162 h = __float22bfloat162_rn(make_float2(a, b));
    union { __hip_bfloat162 h; unsigned int u; } r; r.h = h; return r.u;
}

__device__ __forceinline__ float lrelu(float x) { return x > 0.f ? x : ALPHA * x; }

__device__ __forceinline__ v8bf load8f(const float* p) {
    float4 A = ((const float4*)p)[0];
    float4 B = ((const float4*)p)[1];
    union { v8bf v; unsigned int u[4]; } r;
    r.u[0] = pk2(A.x, A.y); r.u[1] = pk2(A.z, A.w);
    r.u[2] = pk2(B.x, B.y); r.u[3] = pk2(B.z, B.w);
    return r.v;
}

// ---------------------------------------------------------------------------
// Kernel 0: convert + transpose weights to bf16 once.
// WT layout (ushort): [0) WqT 128x128 | [16384) WkT | [32768) WvT | [49152) W1T 128x256
// ---------------------------------------------------------------------------
__global__ __launch_bounds__(256) void prep_kernel(
    const float* __restrict__ Wq, const float* __restrict__ Wk,
    const float* __restrict__ Wv, const float* __restrict__ W1,
    ushort_t* __restrict__ WT)
{
    const int idx = blockIdx.x * 256 + threadIdx.x;
    if (idx < 16384) {
        int k = idx >> 7, n = idx & 127;
        WT[n * 128 + k] = f2bf(Wq[idx]);
    } else if (idx < 32768) {
        int i = idx - 16384; int k = i >> 7, n = i & 127;
        WT[16384 + n * 128 + k] = f2bf(Wk[i]);
    } else if (idx < 49152) {
        int i = idx - 32768; int k = i >> 7, n = i & 127;
        WT[32768 + n * 128 + k] = f2bf(Wv[i]);
    } else if (idx < 81920) {
        int i = idx - 49152; int k = i >> 7, n = i & 127;  // k in [0,256)
        WT[49152 + n * 256 + k] = f2bf(W1[i]);
    }
}

// ---------------------------------------------------------------------------
// Kernel A (R5 rewrite): grid (391, 3) — blockIdx.y selects Wq/Wk/Wv.
// Latency-bound before (occ 15%, 6 waves/CU, 3 serial barrier-phases/block):
// now 1173 independent blocks, ZERO barriers, ZERO LDS. B fragments are
// 16B contiguous reads straight from bf16 WT (96 KB, L2-resident) —
// per-wave B traffic is 32 KB; grid total ~150 MB of L2 reads (~4 µs).
// Stores are at kernel end: no vmcnt(0)-before-barrier drain anymore.
// ---------------------------------------------------------------------------
__global__ __launch_bounds__(256) void qkv_kernel(
    const float* __restrict__ E, const ushort_t* __restrict__ WT,
    const float* __restrict__ bq, const float* __restrict__ bk,
    const float* __restrict__ bv,
    float* __restrict__ Qo, ushort_t* __restrict__ KV)
{
    const int tid  = threadIdx.x;
    const int wave = tid >> 6;
    const int lane = tid & 63;
    const int quad = lane >> 4;
    const int j    = lane & 15;
    const int row0 = blockIdx.x * 128 + wave * 32;
    const int w    = blockIdx.y;                 // 0=Q, 1=K, 2=V (uniform)

    const ushort_t* __restrict__ Wsrc = WT + w * 16384;

    const int ar0 = min(row0 + j,      N_NODES - 1);
    const int ar1 = min(row0 + 16 + j, N_NODES - 1);

    v8bf a0f[4], a1f[4];
#pragma unroll
    for (int ks = 0; ks < 4; ++ks) {
        const int k0 = ks * 32 + quad * 8;
        a0f[ks] = load8f(E + (size_t)ar0 * FDIM + k0);
        a1f[ks] = load8f(E + (size_t)ar1 * FDIM + k0);
    }

    v4f acc[2][8];
#pragma unroll
    for (int rb = 0; rb < 2; ++rb)
#pragma unroll
        for (int c = 0; c < 8; ++c) acc[rb][c] = (v4f){0.f, 0.f, 0.f, 0.f};

#pragma unroll
    for (int ks = 0; ks < 4; ++ks) {
        const int k0 = ks * 32 + quad * 8;
        v8bf b[8];
#pragma unroll
        for (int c = 0; c < 8; ++c)
            b[c] = *(const v8bf*)(Wsrc + (c * 16 + j) * 128 + k0);
#pragma unroll
        for (int c = 0; c < 8; ++c) {
            acc[0][c] = __builtin_amdgcn_mfma_f32_16x16x32_bf16(a0f[ks], b[c], acc[0][c], 0, 0, 0);
            acc[1][c] = __builtin_amdgcn_mfma_f32_16x16x32_bf16(a1f[ks], b[c], acc[1][c], 0, 0, 0);
        }
    }

    const float* __restrict__ bias = (w == 0) ? bq : (w == 1) ? bk : bv;
#pragma unroll
    for (int c = 0; c < 8; ++c) {
        const int col = c * 16 + j;
        const float bv_ = bias[col];
#pragma unroll
        for (int rb = 0; rb < 2; ++rb) {
#pragma unroll
            for (int i = 0; i < 4; ++i) {
                const int r = row0 + rb * 16 + quad * 4 + i;
                if (r < N_NODES) {
                    const float x = lrelu(acc[rb][c][i] + bv_);
                    if (w == 0)      Qo[(size_t)r * HDIM + col] = x;
                    else if (w == 1) KV[(size_t)r * 256 + col] = f2bf(x);        // K half
                    else             KV[(size_t)r * 256 + 128 + col] = f2bf(x);  // V half
                }
            }
        }
    }
}

// ---------------------------------------------------------------------------
// Kernel B (R3/R4-proven): one wave per node, 4 nodes/block, 12500 blocks.
// Reads q (f32) from QP[node], overwrites the same row with pooled (f32) —
// same-wave read-before-write, safe. No LDS, no barriers.
// ---------------------------------------------------------------------------
__global__ __launch_bounds__(256) void attn_kernel(
    float* __restrict__ QP, const ushort_t* __restrict__ KV,
    const int* __restrict__ nbr)
{
    const int tid  = threadIdx.x;
    const int wave = tid >> 6;
    const int lane = tid & 63;
    const int node = __builtin_amdgcn_readfirstlane(blockIdx.x * 4 + wave);

    const float2 qp = ((const float2*)(QP + (size_t)node * HDIM))[lane];

    int idxs[KNB];
    const int* nb = nbr + node * KNB;   // uniform base -> scalar loads
#pragma unroll
    for (int t = 0; t < KNB; ++t) {
        int id = nb[t];
        idxs[t] = ((unsigned)id < (unsigned)N_NODES) ? id : 0;
    }

    float sc[KNB];
#pragma unroll
    for (int t = 0; t < KNB; ++t) {
        const unsigned int kp = ((const unsigned int*)(KV + (size_t)idxs[t] * 256))[lane];
        float p = qp.x * blo(kp) + qp.y * bhi(kp);
#pragma unroll
        for (int off = 32; off >= 1; off >>= 1) p += __shfl_xor(p, off, 64);
        sc[t] = p;
    }

    float m = sc[0];
#pragma unroll
    for (int t = 1; t < KNB; ++t) m = fmaxf(m, sc[t]);
    float s = 0.f;
#pragma unroll
    for (int t = 0; t < KNB; ++t) { sc[t] = __expf(sc[t] - m); s += sc[t]; }
    const float inv = 1.f / s;

    float p0 = 0.f, p1 = 0.f;
#pragma unroll
    for (int t = 0; t < KNB; ++t) {
        const unsigned int vp = ((const unsigned int*)(KV + (size_t)idxs[t] * 256 + 128))[lane];
        const float a = sc[t] * inv;
        p0 += a * blo(vp);
        p1 += a * bhi(vp);
    }

    ((float2*)(QP + (size_t)node * HDIM))[lane] = make_float2(p0, p1);
}

// ---------------------------------------------------------------------------
// Kernel C (R5 rewrite): out = BN(rownorm(lrelu([E,pooled]@W1+b1))).
// Same no-LDS treatment as kernel A: B fragments read straight from W1T
// (64 KB, L2-resident). ONE barrier remains, before the epilogue: it orders
// all pooled reads (half=1 A-loads, drained by the barrier's vmcnt wait)
// before any OutP write — needed only for block 390, whose clamped rows
// make wave 3 read row 49999 while wave 2 owns/writes it. Blocks otherwise
// touch only their own row range — no cross-block hazard (R4-proven).
// ---------------------------------------------------------------------------
__global__ __launch_bounds__(256) void out_kernel(
    const float* __restrict__ E, const ushort_t* __restrict__ W1T,
    const float* __restrict__ b1,
    const float* __restrict__ gamma, const float* __restrict__ beta,
    const float* __restrict__ mmean, const float* __restrict__ mvar,
    float* __restrict__ OutP)   // pooled (in) + out (result)
{
    const int tid  = threadIdx.x;
    const int wave = tid >> 6;
    const int lane = tid & 63;
    const int quad = lane >> 4;
    const int j    = lane & 15;
    const int row0 = blockIdx.x * 128 + wave * 32;

    const int ar0 = min(row0 + j,      N_NODES - 1);
    const int ar1 = min(row0 + 16 + j, N_NODES - 1);

    v4f acc[2][8];
#pragma unroll
    for (int rb = 0; rb < 2; ++rb)
#pragma unroll
        for (int c = 0; c < 8; ++c) acc[rb][c] = (v4f){0.f, 0.f, 0.f, 0.f};

#pragma unroll
    for (int half = 0; half < 2; ++half) {
        const float* __restrict__ Abase = (half == 0) ? E : (const float*)OutP;
        const ushort_t* __restrict__ Wh = W1T + half * 128;
#pragma unroll
        for (int ks = 0; ks < 4; ++ks) {
            const int k0 = ks * 32 + quad * 8;
            v8bf a0 = load8f(Abase + (size_t)ar0 * 128 + k0);
            v8bf a1 = load8f(Abase + (size_t)ar1 * 128 + k0);
            v8bf b[8];
#pragma unroll
            for (int c = 0; c < 8; ++c)
                b[c] = *(const v8bf*)(Wh + (c * 16 + j) * 256 + k0);
#pragma unroll
            for (int c = 0; c < 8; ++c) {
                acc[0][c] = __builtin_amdgcn_mfma_f32_16x16x32_bf16(a0, b[c], acc[0][c], 0, 0, 0);
                acc[1][c] = __builtin_amdgcn_mfma_f32_16x16x32_bf16(a1, b[c], acc[1][c], 0, 0, 0);
            }
        }
    }

    __syncthreads();   // orders pooled reads before epilogue writes (block 390)

    float scale_[8], shift_[8], bias_[8];
#pragma unroll
    for (int c = 0; c < 8; ++c) {
        const int col = c * 16 + j;
        const float sc = gamma[col] * rsqrtf(mvar[col] + BN_EPS);
        scale_[c] = sc;
        shift_[c] = beta[col] - mmean[col] * sc;
        bias_[c]  = b1[col];
    }

#pragma unroll
    for (int rb = 0; rb < 2; ++rb)
#pragma unroll
        for (int c = 0; c < 8; ++c)
#pragma unroll
            for (int i = 0; i < 4; ++i)
                acc[rb][c][i] = lrelu(acc[rb][c][i] + bias_[c]);

#pragma unroll
    for (int rb = 0; rb < 2; ++rb) {
#pragma unroll
        for (int i = 0; i < 4; ++i) {
            float ss = 0.f;
#pragma unroll
            for (int c = 0; c < 8; ++c) ss += acc[rb][c][i] * acc[rb][c][i];
            ss += __shfl_xor(ss, 1, 64);
            ss += __shfl_xor(ss, 2, 64);
            ss += __shfl_xor(ss, 4, 64);
            ss += __shfl_xor(ss, 8, 64);
            const float invn = 1.f / (sqrtf(ss) + 1e-6f);
            const int r = row0 + rb * 16 + quad * 4 + i;
            if (r < N_NODES) {
#pragma unroll
                for (int c = 0; c < 8; ++c)
                    OutP[(size_t)r * HDIM + c * 16 + j] =
                        acc[rb][c][i] * invn * scale_[c] + shift_[c];
            }
        }
    }
}

extern "C" void kernel_launch(void* const* d_in, const int* in_sizes, int n_in,
                              void* d_out, int out_size, void* d_ws, size_t ws_size,
                              hipStream_t stream)
{
    const float* E     = (const float*)d_in[0];
    const int*   nbr   = (const int*)d_in[2];
    const float* Wq    = (const float*)d_in[3];
    const float* bq    = (const float*)d_in[4];
    const float* Wk    = (const float*)d_in[5];
    const float* bk    = (const float*)d_in[6];
    const float* Wv    = (const float*)d_in[7];
    const float* bv    = (const float*)d_in[8];
    const float* W1    = (const float*)d_in[9];
    const float* b1    = (const float*)d_in[10];
    const float* gam   = (const float*)d_in[11];
    const float* bet   = (const float*)d_in[12];
    const float* mmean = (const float*)d_in[13];
    const float* mvar  = (const float*)d_in[14];

    // ws: KV interleaved bf16 (25.6 MB) + WT bf16 (160 KB) = 25.76 MB total
    // (PROVEN budget — R7's 38.56 MB overflowed d_ws and corrupted the
    // harness's pristine buffers). Q (f32) then pooled (f32) share d_out.
    ushort_t* KV = (ushort_t*)d_ws;
    ushort_t* WT = KV + (size_t)N_NODES * 256;
    float* QP = (float*)d_out;

    const int gridA = (N_NODES + 127) / 128;  // 391
    prep_kernel<<<320, 256, 0, stream>>>(Wq, Wk, Wv, W1, WT);
    qkv_kernel<<<dim3(gridA, 3), 256, 0, stream>>>(E, WT, bq, bk, bv, QP, KV);
    attn_kernel<<<N_NODES / 4, 256, 0, stream>>>(QP, KV, nbr);
    out_kernel<<<gridA, 256, 0, stream>>>(E, WT + 49152, b1, gam, bet, mmean, mvar, QP);
}

// Round 2
// 210.101 us; speedup vs baseline: 1.1230x; 1.1230x over previous
//
#include <hip/hip_runtime.h>
#include <hip/hip_bf16.h>

#define N_NODES 50000
#define KNB 16
#define FDIM 128
#define HDIM 128
#define ALPHA 0.3f
#define BN_EPS 1e-3f

typedef __bf16 v8bf __attribute__((ext_vector_type(8)));
typedef float v4f __attribute__((ext_vector_type(4)));
typedef unsigned short ushort_t;

__device__ __forceinline__ float blo(unsigned int u) {
    union { float f; unsigned int i; } x; x.i = u << 16; return x.f;
}
__device__ __forceinline__ float bhi(unsigned int u) {
    union { float f; unsigned int i; } x; x.i = u & 0xffff0000u; return x.f;
}

__device__ __forceinline__ unsigned short f2bf(float f) {
    union { float f; unsigned int u; } x;
    x.f = f;
    unsigned int r = x.u + 0x7fffu + ((x.u >> 16) & 1u);  // RNE
    return (unsigned short)(r >> 16);
}

// packed f32x2 -> bf16x2 (RNE)
__device__ __forceinline__ unsigned int pk2(float a, float b) {
    __hip_bfloat162 h = __float22bfloat162_rn(make_float2(a, b));
    union { __hip_bfloat162 h; unsigned int u; } r; r.h = h; return r.u;
}

__device__ __forceinline__ float lrelu(float x) { return x > 0.f ? x : ALPHA * x; }

__device__ __forceinline__ v8bf load8f(const float* p) {
    float4 A = ((const float4*)p)[0];
    float4 B = ((const float4*)p)[1];
    union { v8bf v; unsigned int u[4]; } r;
    r.u[0] = pk2(A.x, A.y); r.u[1] = pk2(A.z, A.w);
    r.u[2] = pk2(B.x, B.y); r.u[3] = pk2(B.z, B.w);
    return r.v;
}

// ---------------------------------------------------------------------------
// Kernel 0: convert + transpose weights to bf16 once.
// WT layout (ushort): [0) WqT 128x128 | [16384) WkT | [32768) WvT | [49152) W1T 128x256
// ---------------------------------------------------------------------------
__global__ __launch_bounds__(256) void prep_kernel(
    const float* __restrict__ Wq, const float* __restrict__ Wk,
    const float* __restrict__ Wv, const float* __restrict__ W1,
    ushort_t* __restrict__ WT)
{
    const int idx = blockIdx.x * 256 + threadIdx.x;
    if (idx < 16384) {
        int k = idx >> 7, n = idx & 127;
        WT[n * 128 + k] = f2bf(Wq[idx]);
    } else if (idx < 32768) {
        int i = idx - 16384; int k = i >> 7, n = i & 127;
        WT[16384 + n * 128 + k] = f2bf(Wk[i]);
    } else if (idx < 49152) {
        int i = idx - 32768; int k = i >> 7, n = i & 127;
        WT[32768 + n * 128 + k] = f2bf(Wv[i]);
    } else if (idx < 81920) {
        int i = idx - 49152; int k = i >> 7, n = i & 127;  // k in [0,256)
        WT[49152 + n * 256 + k] = f2bf(W1[i]);
    }
}

// ---------------------------------------------------------------------------
// Kernel A (R2 rewrite — full-line store theory):
// R0 (LDS-B, barriers) and R1 (no-LDS, 3x grid) both pinned at ~63 µs with
// all pipes <25% => store-path saturated by 2B/4B scattered stores (32-64B
// segments, partial-line L2 RMW). Fix:
//  * operand-SWAPPED MFMA (mfma(b,a,acc) => D^T: lane holds 4 CONSECUTIVE
//    output cols of one row — A/B frag layouts are symmetric so swap = transpose)
//  * wave-private LDS staging tile, then dwordx4 copy-out: 1KB fully
//    contiguous per store instruction (2 rows/inst), 16 stores per tile.
// Single block does Q,K,V (E/A-frags read+converted once, FETCH ~13MB);
// B frags read direct from L2-hot WT (no barriers anywhere in this kernel —
// LDS regions are wave-private, lgkmcnt ordering only).
// ---------------------------------------------------------------------------
#define QSTRIDE 560   // bytes/row in Q staging tile (140 dwords: 2-way banks)
#define KVSTRIDE 528  // bytes/row in KV staging tile (132 dwords)
#define WTILE 18432   // per-wave LDS region (>= 32*560), 16B aligned

__global__ __launch_bounds__(256) void qkv_kernel(
    const float* __restrict__ E, const ushort_t* __restrict__ WT,
    const float* __restrict__ bq, const float* __restrict__ bk,
    const float* __restrict__ bv,
    float* __restrict__ Qo, ushort_t* __restrict__ KV)
{
    __shared__ char smem[4 * WTILE];

    const int tid  = threadIdx.x;
    const int wave = tid >> 6;
    const int lane = tid & 63;
    const int quad = lane >> 4;
    const int j    = lane & 15;
    const int row0 = blockIdx.x * 128 + wave * 32;

    char* const wbase = smem + wave * WTILE;

    const int ar0 = min(row0 + j,      N_NODES - 1);
    const int ar1 = min(row0 + 16 + j, N_NODES - 1);

    v8bf a0f[4], a1f[4];
#pragma unroll
    for (int ks = 0; ks < 4; ++ks) {
        const int k0 = ks * 32 + quad * 8;
        a0f[ks] = load8f(E + (size_t)ar0 * FDIM + k0);
        a1f[ks] = load8f(E + (size_t)ar1 * FDIM + k0);
    }

    const float* biases[3] = {bq, bk, bv};

    for (int w = 0; w < 3; ++w) {
        const ushort_t* __restrict__ Wsrc = WT + w * 16384;

        v4f acc[2][8];
#pragma unroll
        for (int rb = 0; rb < 2; ++rb)
#pragma unroll
            for (int c = 0; c < 8; ++c) acc[rb][c] = (v4f){0.f, 0.f, 0.f, 0.f};

#pragma unroll
        for (int ks = 0; ks < 4; ++ks) {
            const int k0 = ks * 32 + quad * 8;
            v8bf b[8];
#pragma unroll
            for (int c = 0; c < 8; ++c)
                b[c] = *(const v8bf*)(Wsrc + (c * 16 + j) * 128 + k0);
            // SWAPPED operands: D^T — lane (quad,j) holds rows row0+rb*16+j,
            // cols c*16+quad*4 .. +3 (4 consecutive columns).
#pragma unroll
            for (int c = 0; c < 8; ++c) {
                acc[0][c] = __builtin_amdgcn_mfma_f32_16x16x32_bf16(b[c], a0f[ks], acc[0][c], 0, 0, 0);
                acc[1][c] = __builtin_amdgcn_mfma_f32_16x16x32_bf16(b[c], a1f[ks], acc[1][c], 0, 0, 0);
            }
        }

        const float* __restrict__ bias = biases[w];

        if (w == 0) {
            // ---- Q: stage f32 tile (32 rows x 512B) then 1KB-linear stores
#pragma unroll
            for (int rb = 0; rb < 2; ++rb)
#pragma unroll
                for (int c = 0; c < 8; ++c) {
                    const float4 bb = ((const float4*)bias)[c * 4 + quad];
                    v4f v = acc[rb][c];
                    v[0] = lrelu(v[0] + bb.x); v[1] = lrelu(v[1] + bb.y);
                    v[2] = lrelu(v[2] + bb.z); v[3] = lrelu(v[3] + bb.w);
                    *(v4f*)(wbase + (rb * 16 + j) * QSTRIDE + (c * 16 + quad * 4) * 4) = v;
                }
#pragma unroll
            for (int t = 0; t < 16; ++t) {
                const int r  = 2 * t + (lane >> 5);
                const v4f v  = *(const v4f*)(wbase + r * QSTRIDE + (lane & 31) * 16);
                const int gr = row0 + r;
                if (gr < N_NODES)
                    *(v4f*)(Qo + (size_t)gr * HDIM + (lane & 31) * 4) = v;
            }
        } else {
            // ---- K (w=1) / V (w=2): pack bf16 into interleaved KV tile row
            const int voff = (w == 2) ? 256 : 0;  // V half at +256B in row
#pragma unroll
            for (int rb = 0; rb < 2; ++rb)
#pragma unroll
                for (int c = 0; c < 8; ++c) {
                    const float4 bb = ((const float4*)bias)[c * 4 + quad];
                    const v4f v = acc[rb][c];
                    uint2 u;
                    u.x = pk2(lrelu(v[0] + bb.x), lrelu(v[1] + bb.y));
                    u.y = pk2(lrelu(v[2] + bb.z), lrelu(v[3] + bb.w));
                    *(uint2*)(wbase + (rb * 16 + j) * KVSTRIDE + (c * 16 + quad * 4) * 2 + voff) = u;
                }
            if (w == 2) {
                // full 512B KV rows staged — 1KB-linear copy-out
#pragma unroll
                for (int t = 0; t < 16; ++t) {
                    const int r  = 2 * t + (lane >> 5);
                    const uint4 v = *(const uint4*)(wbase + r * KVSTRIDE + (lane & 31) * 16);
                    const int gr = row0 + r;
                    if (gr < N_NODES)   // guard: row 50000+ would smash WT in ws
                        *(uint4*)((char*)KV + (size_t)gr * 512 + (lane & 31) * 16) = v;
                }
            }
        }
    }
}

// ---------------------------------------------------------------------------
// Kernel B (R3/R4-proven): one wave per node, 4 nodes/block, 12500 blocks.
// Reads q (f32) from QP[node], overwrites the same row with pooled (f32) —
// same-wave read-before-write, safe. No LDS, no barriers.
// ---------------------------------------------------------------------------
__global__ __launch_bounds__(256) void attn_kernel(
    float* __restrict__ QP, const ushort_t* __restrict__ KV,
    const int* __restrict__ nbr)
{
    const int tid  = threadIdx.x;
    const int wave = tid >> 6;
    const int lane = tid & 63;
    const int node = __builtin_amdgcn_readfirstlane(blockIdx.x * 4 + wave);

    const float2 qp = ((const float2*)(QP + (size_t)node * HDIM))[lane];

    int idxs[KNB];
    const int* nb = nbr + node * KNB;   // uniform base -> scalar loads
#pragma unroll
    for (int t = 0; t < KNB; ++t) {
        int id = nb[t];
        idxs[t] = ((unsigned)id < (unsigned)N_NODES) ? id : 0;
    }

    float sc[KNB];
#pragma unroll
    for (int t = 0; t < KNB; ++t) {
        const unsigned int kp = ((const unsigned int*)(KV + (size_t)idxs[t] * 256))[lane];
        float p = qp.x * blo(kp) + qp.y * bhi(kp);
#pragma unroll
        for (int off = 32; off >= 1; off >>= 1) p += __shfl_xor(p, off, 64);
        sc[t] = p;
    }

    float m = sc[0];
#pragma unroll
    for (int t = 1; t < KNB; ++t) m = fmaxf(m, sc[t]);
    float s = 0.f;
#pragma unroll
    for (int t = 0; t < KNB; ++t) { sc[t] = __expf(sc[t] - m); s += sc[t]; }
    const float inv = 1.f / s;

    float p0 = 0.f, p1 = 0.f;
#pragma unroll
    for (int t = 0; t < KNB; ++t) {
        const unsigned int vp = ((const unsigned int*)(KV + (size_t)idxs[t] * 256 + 128))[lane];
        const float a = sc[t] * inv;
        p0 += a * blo(vp);
        p1 += a * bhi(vp);
    }

    ((float2*)(QP + (size_t)node * HDIM))[lane] = make_float2(p0, p1);
}

// ---------------------------------------------------------------------------
// Kernel C (R0-proven, reverted): out = BN(rownorm(lrelu([E,pooled]@W1+b1))).
// pooled (f32) lives in d_out; result overwrites d_out. The barrier at the
// end of half=1 orders all pooled reads before any epilogue write within a
// block; blocks read/write only their own row range (clamped reads in block
// 390 target its own rows) — no cross-block hazard.
// ---------------------------------------------------------------------------
__global__ __launch_bounds__(256) void out_kernel(
    const float* __restrict__ E, const ushort_t* __restrict__ W1T,
    const float* __restrict__ b1,
    const float* __restrict__ gamma, const float* __restrict__ beta,
    const float* __restrict__ mmean, const float* __restrict__ mvar,
    float* __restrict__ OutP)   // pooled (in) + out (result)
{
    __shared__ ushort_t sW[128 * 136];

    const int tid  = threadIdx.x;
    const int wave = tid >> 6;
    const int lane = tid & 63;
    const int quad = lane >> 4;
    const int j    = lane & 15;
    const int row0 = blockIdx.x * 128 + wave * 32;

    const int ar0 = min(row0 + j,      N_NODES - 1);
    const int ar1 = min(row0 + 16 + j, N_NODES - 1);

    v4f acc[2][8];
#pragma unroll
    for (int rb = 0; rb < 2; ++rb)
#pragma unroll
        for (int c = 0; c < 8; ++c) acc[rb][c] = (v4f){0.f, 0.f, 0.f, 0.f};

    for (int half = 0; half < 2; ++half) {
        for (int i = tid; i < 2048; i += 256) {
            int n = i >> 4, kc = i & 15;
            *(uint4*)(&sW[n * 136 + kc * 8]) =
                *(const uint4*)(W1T + n * 256 + half * 128 + kc * 8);
        }
        __syncthreads();

        const float* Abase = (half == 0) ? E : (const float*)OutP;
#pragma unroll
        for (int ks = 0; ks < 4; ++ks) {
            const int k0 = ks * 32 + quad * 8;
            v8bf a0 = load8f(Abase + (size_t)ar0 * 128 + k0);
            v8bf a1 = load8f(Abase + (size_t)ar1 * 128 + k0);
            v8bf b[8];
#pragma unroll
            for (int c = 0; c < 8; ++c)
                b[c] = *(const v8bf*)(&sW[(c * 16 + j) * 136 + k0]);
#pragma unroll
            for (int c = 0; c < 8; ++c) {
                acc[0][c] = __builtin_amdgcn_mfma_f32_16x16x32_bf16(a0, b[c], acc[0][c], 0, 0, 0);
                acc[1][c] = __builtin_amdgcn_mfma_f32_16x16x32_bf16(a1, b[c], acc[1][c], 0, 0, 0);
            }
        }
        __syncthreads();   // orders pooled reads before epilogue writes
    }

    float scale_[8], shift_[8], bias_[8];
#pragma unroll
    for (int c = 0; c < 8; ++c) {
        const int col = c * 16 + j;
        const float sc = gamma[col] * rsqrtf(mvar[col] + BN_EPS);
        scale_[c] = sc;
        shift_[c] = beta[col] - mmean[col] * sc;
        bias_[c]  = b1[col];
    }

#pragma unroll
    for (int rb = 0; rb < 2; ++rb)
#pragma unroll
        for (int c = 0; c < 8; ++c)
#pragma unroll
            for (int i = 0; i < 4; ++i)
                acc[rb][c][i] = lrelu(acc[rb][c][i] + bias_[c]);

#pragma unroll
    for (int rb = 0; rb < 2; ++rb) {
#pragma unroll
        for (int i = 0; i < 4; ++i) {
            float ss = 0.f;
#pragma unroll
            for (int c = 0; c < 8; ++c) ss += acc[rb][c][i] * acc[rb][c][i];
            ss += __shfl_xor(ss, 1, 64);
            ss += __shfl_xor(ss, 2, 64);
            ss += __shfl_xor(ss, 4, 64);
            ss += __shfl_xor(ss, 8, 64);
            const float invn = 1.f / (sqrtf(ss) + 1e-6f);
            const int r = row0 + rb * 16 + quad * 4 + i;
            if (r < N_NODES) {
#pragma unroll
                for (int c = 0; c < 8; ++c)
                    OutP[(size_t)r * HDIM + c * 16 + j] =
                        acc[rb][c][i] * invn * scale_[c] + shift_[c];
            }
        }
    }
}

extern "C" void kernel_launch(void* const* d_in, const int* in_sizes, int n_in,
                              void* d_out, int out_size, void* d_ws, size_t ws_size,
                              hipStream_t stream)
{
    const float* E     = (const float*)d_in[0];
    const int*   nbr   = (const int*)d_in[2];
    const float* Wq    = (const float*)d_in[3];
    const float* bq    = (const float*)d_in[4];
    const float* Wk    = (const float*)d_in[5];
    const float* bk    = (const float*)d_in[6];
    const float* Wv    = (const float*)d_in[7];
    const float* bv    = (const float*)d_in[8];
    const float* W1    = (const float*)d_in[9];
    const float* b1    = (const float*)d_in[10];
    const float* gam   = (const float*)d_in[11];
    const float* bet   = (const float*)d_in[12];
    const float* mmean = (const float*)d_in[13];
    const float* mvar  = (const float*)d_in[14];

    // ws: KV interleaved bf16 (25.6 MB) + WT bf16 (160 KB) = 25.76 MB total
    // (PROVEN budget — R7's 38.56 MB overflowed d_ws and corrupted the
    // harness's pristine buffers). Q (f32) then pooled (f32) share d_out.
    ushort_t* KV = (ushort_t*)d_ws;
    ushort_t* WT = KV + (size_t)N_NODES * 256;
    float* QP = (float*)d_out;

    const int gridA = (N_NODES + 127) / 128;  // 391
    prep_kernel<<<320, 256, 0, stream>>>(Wq, Wk, Wv, W1, WT);
    qkv_kernel<<<gridA, 256, 0, stream>>>(E, WT, bq, bk, bv, QP, KV);
    attn_kernel<<<N_NODES / 4, 256, 0, stream>>>(QP, KV, nbr);
    out_kernel<<<gridA, 256, 0, stream>>>(E, WT + 49152, b1, gam, bet, mmean, mvar, QP);
}